// Round 2
// baseline (2482.077 us; speedup 1.0000x reference)
//
#include <hip/hip_runtime.h>

#define N_NODES 200000
#define N_EDGES 400000
#define N_GRAPHS 64
#define HDIM 128
#define INDIM 5
#define LN_EPS 1e-5f

// aggr[N*INDIM] = x  (f32 copy, small)
__global__ void init_aggr0(const float* __restrict__ x, float* __restrict__ aggr) {
    int i = blockIdx.x * blockDim.x + threadIdx.x;
    if (i < N_NODES * INDIM) aggr[i] = x[i];
}

// f32 copy (float4)
__global__ void copy_f32x4(const float4* __restrict__ src, float4* __restrict__ dst, int n4) {
    int i = blockIdx.x * blockDim.x + threadIdx.x;
    if (i < n4) dst[i] = src[i];
}

// layer 0 edges: din=5
__global__ void edge_l0(const float* __restrict__ x, const int* __restrict__ ei,
                        const float* __restrict__ ea,
                        const float* __restrict__ ew, const float* __restrict__ eb,
                        float* __restrict__ aggr) {
    int e = blockIdx.x * blockDim.x + threadIdx.x;
    if (e >= N_EDGES) return;
    int src = ei[e], dst = ei[N_EDGES + e];
    float a = ea[e];
#pragma unroll
    for (int j = 0; j < INDIM; ++j) {
        float m = x[src * INDIM + j] + a * ew[j] + eb[j];
        m = fmaxf(m, 0.f);
        unsafeAtomicAdd(&aggr[dst * INDIM + j], m);
    }
}

// layers 1/2 edges: din=128. One thread per (edge, 4-channel group).
__global__ __launch_bounds__(256) void edge_l128(const float* __restrict__ x, const int* __restrict__ ei,
                                                 const float* __restrict__ ea,
                                                 const float* __restrict__ ew,
                                                 const float* __restrict__ eb,
                                                 float* __restrict__ aggr) {
    unsigned idx = blockIdx.x * 256u + threadIdx.x;  // E*32 total threads
    int e = idx >> 5;
    int j4 = (idx & 31);           // float4 group
    int j = j4 * 4;
    int src = ei[e], dst = ei[N_EDGES + e];
    float a = ea[e];
    float4 xv = *(const float4*)&x[src * HDIM + j];
    float4 wv = *(const float4*)&ew[j];
    float4 bv = *(const float4*)&eb[j];
    float m0 = fmaxf(xv.x + a * wv.x + bv.x, 0.f);
    float m1 = fmaxf(xv.y + a * wv.y + bv.y, 0.f);
    float m2 = fmaxf(xv.z + a * wv.z + bv.z, 0.f);
    float m3 = fmaxf(xv.w + a * wv.w + bv.w, 0.f);
    float* drow = &aggr[dst * HDIM + j];
    unsafeAtomicAdd(drow + 0, m0);
    unsafeAtomicAdd(drow + 1, m1);
    unsafeAtomicAdd(drow + 2, m2);
    unsafeAtomicAdd(drow + 3, m3);
}

// Fused MLP + LayerNorm + ReLU. 128 threads = channel j; 4 nodes per block.
template <int DIN>
__global__ __launch_bounds__(128) void node_kernel(const float* __restrict__ hin,
                                                   const float* __restrict__ w1,
                                                   const float* __restrict__ b1,
                                                   const float* __restrict__ w2,
                                                   const float* __restrict__ b2,
                                                   const float* __restrict__ g,
                                                   const float* __restrict__ bt,
                                                   float* __restrict__ xout) {
    constexpr int NB = 4;
    int node0 = blockIdx.x * NB;
    int j = threadIdx.x;
    __shared__ float h[NB][DIN];
    __shared__ float t1[NB][HDIM];
    __shared__ float wsum[NB][2], wsq[NB][2];

    for (int n = 0; n < NB; ++n)
        if (j < DIN) h[n][j] = hin[(node0 + n) * DIN + j];
    __syncthreads();

    float b1j = b1[j];
    float acc[NB];
#pragma unroll
    for (int n = 0; n < NB; ++n) acc[n] = b1j;
#pragma unroll 8
    for (int k = 0; k < DIN; ++k) {
        float w = w1[k * HDIM + j];
#pragma unroll
        for (int n = 0; n < NB; ++n) acc[n] += h[n][k] * w;
    }
#pragma unroll
    for (int n = 0; n < NB; ++n) t1[n][j] = fmaxf(acc[n], 0.f);
    __syncthreads();

    float b2j = b2[j];
    float acc2[NB];
#pragma unroll
    for (int n = 0; n < NB; ++n) acc2[n] = b2j;
#pragma unroll 8
    for (int k = 0; k < HDIM; ++k) {
        float w = w2[k * HDIM + j];
#pragma unroll
        for (int n = 0; n < NB; ++n) acc2[n] += t1[n][k] * w;
    }

    int wid = j >> 6, lane = j & 63;
#pragma unroll
    for (int n = 0; n < NB; ++n) {
        float s = acc2[n], ss = acc2[n] * acc2[n];
        for (int off = 32; off; off >>= 1) {
            s += __shfl_down(s, off);
            ss += __shfl_down(ss, off);
        }
        if (lane == 0) { wsum[n][wid] = s; wsq[n][wid] = ss; }
    }
    __syncthreads();

    float gj = g[j], btj = bt[j];
#pragma unroll
    for (int n = 0; n < NB; ++n) {
        float sum = wsum[n][0] + wsum[n][1];
        float sq = wsq[n][0] + wsq[n][1];
        float mu = sum * (1.f / HDIM);
        float var = sq * (1.f / HDIM) - mu * mu;
        float inv = rsqrtf(var + LN_EPS);
        float o = (acc2[n] - mu) * inv * gj + btj;
        xout[(node0 + n) * HDIM + j] = fmaxf(o, 0.f);
    }
}

// Segmented pooling over sorted batch. Block = 128 channels, 256 nodes per block.
#define NPB 256
__global__ __launch_bounds__(128) void pool_partial(const float* __restrict__ x,
                                                    const int* __restrict__ batch,
                                                    float* __restrict__ pool, int* __restrict__ cnt) {
    int j = threadIdx.x;
    int start = blockIdx.x * NPB;
    if (start >= N_NODES) return;
    int end = min(start + NPB, N_NODES);
    int cur = batch[start];
    float acc = 0.f;
    int localcnt = 0;
    for (int i = start; i < end; ++i) {
        int gi = batch[i];
        if (gi != cur) {
            unsafeAtomicAdd(&pool[cur * HDIM + j], acc);
            if (j == 0) atomicAdd(&cnt[cur], localcnt);
            acc = 0.f; localcnt = 0; cur = gi;
        }
        acc += x[i * HDIM + j];
        ++localcnt;
    }
    unsafeAtomicAdd(&pool[cur * HDIM + j], acc);
    if (j == 0) atomicAdd(&cnt[cur], localcnt);
}

__global__ void pool_final(const float* __restrict__ pool, const int* __restrict__ cnt,
                           float* __restrict__ out) {
    int g = blockIdx.x, j = threadIdx.x;
    float add = pool[g * HDIM + j];
    float c = (float)max(cnt[g], 1);
    out[g * (2 * HDIM) + j] = add / c;
    out[g * (2 * HDIM) + HDIM + j] = add;
}

extern "C" void kernel_launch(void* const* d_in, const int* in_sizes, int n_in,
                              void* d_out, int out_size, void* d_ws, size_t ws_size,
                              hipStream_t stream) {
    const float* x_in = (const float*)d_in[0];
    const int* ei = (const int*)d_in[1];
    const float* ea = (const float*)d_in[2];
    const int* batch = (const int*)d_in[3];
    const float* P[24];
    for (int i = 0; i < 24; ++i) P[i] = (const float*)d_in[4 + i];
    // per layer l (base 8l): 0=ew 1=eb 2=w1 3=b1 4=w2 5=b2 6=g 7=bt

    float* x_cur = (float*)d_ws;                       // N*128 f32
    float* aggr = x_cur + (size_t)N_NODES * HDIM;      // N*128 f32
    float* pool = aggr + (size_t)N_NODES * HDIM;       // G*128 f32
    int* cnt = (int*)(pool + N_GRAPHS * HDIM);         // G int
    float* out = (float*)d_out;

    // ---- Layer 0 (din = 5) ----
    init_aggr0<<<(N_NODES * INDIM + 255) / 256, 256, 0, stream>>>(x_in, aggr);
    edge_l0<<<(N_EDGES + 255) / 256, 256, 0, stream>>>(x_in, ei, ea, P[0], P[1], aggr);
    node_kernel<INDIM><<<N_NODES / 4, 128, 0, stream>>>(aggr, P[2], P[3], P[4], P[5], P[6], P[7], x_cur);

    // ---- Layers 1, 2 (din = 128) ----
    for (int l = 1; l < 3; ++l) {
        const float* const* Q = P + 8 * l;
        copy_f32x4<<<(N_NODES * HDIM / 4 + 255) / 256, 256, 0, stream>>>(
            (const float4*)x_cur, (float4*)aggr, N_NODES * HDIM / 4);
        edge_l128<<<(N_EDGES * 32) / 256, 256, 0, stream>>>(x_cur, ei, ea, Q[0], Q[1], aggr);
        node_kernel<HDIM><<<N_NODES / 4, 128, 0, stream>>>(aggr, Q[2], Q[3], Q[4], Q[5], Q[6], Q[7], x_cur);
    }

    // ---- Pooling ----
    hipMemsetAsync(pool, 0, N_GRAPHS * HDIM * sizeof(float) + N_GRAPHS * sizeof(int), stream);
    pool_partial<<<(N_NODES + NPB - 1) / NPB, 128, 0, stream>>>(x_cur, batch, pool, cnt);
    pool_final<<<N_GRAPHS, HDIM, 0, stream>>>(pool, cnt, out);
}

// Round 3
// 1109.466 us; speedup vs baseline: 2.2372x; 2.2372x over previous
//
#include <hip/hip_runtime.h>

#define N_NODES 200000
#define N_EDGES 400000
#define N_GRAPHS 64
#define HDIM 128
#define INDIM 5
#define LN_EPS 1e-5f

// ---------------- CSR build ----------------

__global__ void hist_kernel(const int* __restrict__ ei, int* __restrict__ deg) {
    int e = blockIdx.x * blockDim.x + threadIdx.x;
    if (e < N_EDGES) atomicAdd(&deg[ei[N_EDGES + e]], 1);
}

#define SCAN_CHUNK 1024
#define SCAN_BLOCKS ((N_NODES + SCAN_CHUNK - 1) / SCAN_CHUNK)  // 196

__global__ __launch_bounds__(256) void scan_phaseA(const int* __restrict__ deg, int* __restrict__ bsums) {
    __shared__ int red[256];
    int t = threadIdx.x;
    int base = blockIdx.x * SCAN_CHUNK + t * 4;
    int s = 0;
#pragma unroll
    for (int k = 0; k < 4; ++k) {
        int i = base + k;
        s += (i < N_NODES) ? deg[i] : 0;
    }
    red[t] = s;
    __syncthreads();
    for (int off = 128; off; off >>= 1) {
        if (t < off) red[t] += red[t + off];
        __syncthreads();
    }
    if (t == 0) bsums[blockIdx.x] = red[0];
}

__global__ void scan_phaseB(int* __restrict__ bsums, int* __restrict__ row_ptr) {
    if (threadIdx.x == 0) {
        int run = 0;
        for (int i = 0; i < SCAN_BLOCKS; ++i) {
            int v = bsums[i];
            bsums[i] = run;
            run += v;
        }
        row_ptr[N_NODES] = run;  // == N_EDGES
    }
}

__global__ __launch_bounds__(256) void scan_phaseC(const int* __restrict__ deg,
                                                   const int* __restrict__ bsums,
                                                   int* __restrict__ row_ptr) {
    __shared__ int ts[256];
    int t = threadIdx.x;
    int base = blockIdx.x * SCAN_CHUNK + t * 4;
    int v[4];
    int s = 0;
#pragma unroll
    for (int k = 0; k < 4; ++k) {
        int i = base + k;
        v[k] = (i < N_NODES) ? deg[i] : 0;
        s += v[k];
    }
    ts[t] = s;
    __syncthreads();
    for (int off = 1; off < 256; off <<= 1) {
        int add = (t >= off) ? ts[t - off] : 0;
        __syncthreads();
        ts[t] += add;
        __syncthreads();
    }
    int run = bsums[blockIdx.x] + ts[t] - s;  // exclusive prefix for this thread
#pragma unroll
    for (int k = 0; k < 4; ++k) {
        int i = base + k;
        if (i < N_NODES) row_ptr[i] = run;
        run += v[k];
    }
}

__global__ void scatter_kernel(const int* __restrict__ ei, const float* __restrict__ ea,
                               const int* __restrict__ row_ptr, int* __restrict__ cursor,
                               int* __restrict__ csr_src, float* __restrict__ csr_val) {
    int e = blockIdx.x * blockDim.x + threadIdx.x;
    if (e >= N_EDGES) return;
    int d = ei[N_EDGES + e];
    int pos = atomicAdd(&cursor[d], 1);
    int slot = row_ptr[d] + pos;
    csr_src[slot] = ei[e];
    csr_val[slot] = ea[e];
}

// ---------------- Aggregation (gather, no atomics) ----------------

// layer 0: din = 5. One thread per node.
__global__ __launch_bounds__(256) void agg5(const float* __restrict__ x,
                                            const int* __restrict__ row_ptr,
                                            const int* __restrict__ csr_src,
                                            const float* __restrict__ csr_val,
                                            const float* __restrict__ ew, const float* __restrict__ eb,
                                            float* __restrict__ aggr) {
    int node = blockIdx.x * blockDim.x + threadIdx.x;
    if (node >= N_NODES) return;
    float w[INDIM], b[INDIM], acc[INDIM];
#pragma unroll
    for (int j = 0; j < INDIM; ++j) {
        w[j] = ew[j];
        b[j] = eb[j];
        acc[j] = x[node * INDIM + j];
    }
    int beg = row_ptr[node], end = row_ptr[node + 1];
    for (int e = beg; e < end; ++e) {
        int s = csr_src[e];
        float a = csr_val[e];
#pragma unroll
        for (int j = 0; j < INDIM; ++j)
            acc[j] += fmaxf(x[s * INDIM + j] + a * w[j] + b[j], 0.f);
    }
#pragma unroll
    for (int j = 0; j < INDIM; ++j) aggr[node * INDIM + j] = acc[j];
}

// layers 1/2: din = 128. 32 threads per node (float4 channels), 8 nodes/block.
__global__ __launch_bounds__(256) void agg128(const float* __restrict__ x,
                                              const int* __restrict__ row_ptr,
                                              const int* __restrict__ csr_src,
                                              const float* __restrict__ csr_val,
                                              const float* __restrict__ ew, const float* __restrict__ eb,
                                              float* __restrict__ aggr) {
    int t = threadIdx.x;
    int node = blockIdx.x * 8 + (t >> 5);
    int c = (t & 31) * 4;
    float4 w4 = *(const float4*)&ew[c];
    float4 b4 = *(const float4*)&eb[c];
    float4 acc = *(const float4*)&x[(size_t)node * HDIM + c];
    int beg = row_ptr[node], end = row_ptr[node + 1];
    for (int e = beg; e < end; ++e) {
        int s = csr_src[e];
        float a = csr_val[e];
        float4 xv = *(const float4*)&x[(size_t)s * HDIM + c];
        acc.x += fmaxf(xv.x + a * w4.x + b4.x, 0.f);
        acc.y += fmaxf(xv.y + a * w4.y + b4.y, 0.f);
        acc.z += fmaxf(xv.z + a * w4.z + b4.z, 0.f);
        acc.w += fmaxf(xv.w + a * w4.w + b4.w, 0.f);
    }
    *(float4*)&aggr[(size_t)node * HDIM + c] = acc;
}

// ---------------- Fused MLP + LayerNorm + ReLU ----------------
// 128 threads = channel j; 8 nodes per block.
template <int DIN>
__global__ __launch_bounds__(128) void node_kernel(const float* __restrict__ hin,
                                                   const float* __restrict__ w1,
                                                   const float* __restrict__ b1,
                                                   const float* __restrict__ w2,
                                                   const float* __restrict__ b2,
                                                   const float* __restrict__ g,
                                                   const float* __restrict__ bt,
                                                   float* __restrict__ xout) {
    constexpr int NB = 8;
    int node0 = blockIdx.x * NB;
    int j = threadIdx.x;
    __shared__ float h[NB][DIN];
    __shared__ float t1[NB][HDIM];
    __shared__ float wsum[NB][2], wsq[NB][2];

#pragma unroll
    for (int n = 0; n < NB; ++n)
        if (j < DIN) h[n][j] = hin[(node0 + n) * DIN + j];
    __syncthreads();

    float b1j = b1[j];
    float acc[NB];
#pragma unroll
    for (int n = 0; n < NB; ++n) acc[n] = b1j;
#pragma unroll 4
    for (int k = 0; k < DIN; ++k) {
        float w = w1[k * HDIM + j];
#pragma unroll
        for (int n = 0; n < NB; ++n) acc[n] += h[n][k] * w;
    }
#pragma unroll
    for (int n = 0; n < NB; ++n) t1[n][j] = fmaxf(acc[n], 0.f);
    __syncthreads();

    float b2j = b2[j];
    float acc2[NB];
#pragma unroll
    for (int n = 0; n < NB; ++n) acc2[n] = b2j;
#pragma unroll 4
    for (int k = 0; k < HDIM; ++k) {
        float w = w2[k * HDIM + j];
#pragma unroll
        for (int n = 0; n < NB; ++n) acc2[n] += t1[n][k] * w;
    }

    int wid = j >> 6, lane = j & 63;
#pragma unroll
    for (int n = 0; n < NB; ++n) {
        float s = acc2[n], ss = acc2[n] * acc2[n];
        for (int off = 32; off; off >>= 1) {
            s += __shfl_down(s, off);
            ss += __shfl_down(ss, off);
        }
        if (lane == 0) { wsum[n][wid] = s; wsq[n][wid] = ss; }
    }
    __syncthreads();

    float gj = g[j], btj = bt[j];
#pragma unroll
    for (int n = 0; n < NB; ++n) {
        float sum = wsum[n][0] + wsum[n][1];
        float sq = wsq[n][0] + wsq[n][1];
        float mu = sum * (1.f / HDIM);
        float var = sq * (1.f / HDIM) - mu * mu;
        float inv = rsqrtf(var + LN_EPS);
        float o = (acc2[n] - mu) * inv * gj + btj;
        xout[(node0 + n) * HDIM + j] = fmaxf(o, 0.f);
    }
}

// ---------------- Pooling ----------------
#define NPB 256
__global__ __launch_bounds__(128) void pool_partial(const float* __restrict__ x,
                                                    const int* __restrict__ batch,
                                                    float* __restrict__ pool, int* __restrict__ cnt) {
    int j = threadIdx.x;
    int start = blockIdx.x * NPB;
    if (start >= N_NODES) return;
    int end = min(start + NPB, N_NODES);
    int cur = batch[start];
    float acc = 0.f;
    int localcnt = 0;
    for (int i = start; i < end; ++i) {
        int gi = batch[i];
        if (gi != cur) {
            unsafeAtomicAdd(&pool[cur * HDIM + j], acc);
            if (j == 0) atomicAdd(&cnt[cur], localcnt);
            acc = 0.f; localcnt = 0; cur = gi;
        }
        acc += x[i * HDIM + j];
        ++localcnt;
    }
    unsafeAtomicAdd(&pool[cur * HDIM + j], acc);
    if (j == 0) atomicAdd(&cnt[cur], localcnt);
}

__global__ void pool_final(const float* __restrict__ pool, const int* __restrict__ cnt,
                           float* __restrict__ out) {
    int g = blockIdx.x, j = threadIdx.x;
    float add = pool[g * HDIM + j];
    float c = (float)max(cnt[g], 1);
    out[g * (2 * HDIM) + j] = add / c;
    out[g * (2 * HDIM) + HDIM + j] = add;
}

extern "C" void kernel_launch(void* const* d_in, const int* in_sizes, int n_in,
                              void* d_out, int out_size, void* d_ws, size_t ws_size,
                              hipStream_t stream) {
    const float* x_in = (const float*)d_in[0];
    const int* ei = (const int*)d_in[1];
    const float* ea = (const float*)d_in[2];
    const int* batch = (const int*)d_in[3];
    const float* P[24];
    for (int i = 0; i < 24; ++i) P[i] = (const float*)d_in[4 + i];
    // per layer l (base 8l): 0=ew 1=eb 2=w1 3=b1 4=w2 5=b2 6=g 7=bt

    float* x_cur = (float*)d_ws;                         // N*128 f32
    float* aggr = x_cur + (size_t)N_NODES * HDIM;        // N*128 f32
    float* pool = aggr + (size_t)N_NODES * HDIM;         // G*128 f32
    int* cnt = (int*)(pool + N_GRAPHS * HDIM);           // G
    int* deg = cnt + N_GRAPHS;                           // N (histogram, then cursor)
    int* row_ptr = deg + N_NODES;                        // N+1
    int* bsums = row_ptr + N_NODES + 1;                  // SCAN_BLOCKS (pad 256)
    int* csr_src = bsums + 256;                          // E
    float* csr_val = (float*)(csr_src + N_EDGES);        // E
    float* out = (float*)d_out;

    // ---- CSR build (by destination) ----
    hipMemsetAsync(deg, 0, N_NODES * sizeof(int), stream);
    hist_kernel<<<(N_EDGES + 255) / 256, 256, 0, stream>>>(ei, deg);
    scan_phaseA<<<SCAN_BLOCKS, 256, 0, stream>>>(deg, bsums);
    scan_phaseB<<<1, 64, 0, stream>>>(bsums, row_ptr);
    scan_phaseC<<<SCAN_BLOCKS, 256, 0, stream>>>(deg, bsums, row_ptr);
    hipMemsetAsync(deg, 0, N_NODES * sizeof(int), stream);
    scatter_kernel<<<(N_EDGES + 255) / 256, 256, 0, stream>>>(ei, ea, row_ptr, deg, csr_src, csr_val);

    // ---- Layer 0 (din = 5) ----
    agg5<<<(N_NODES + 255) / 256, 256, 0, stream>>>(x_in, row_ptr, csr_src, csr_val, P[0], P[1], aggr);
    node_kernel<INDIM><<<N_NODES / 8, 128, 0, stream>>>(aggr, P[2], P[3], P[4], P[5], P[6], P[7], x_cur);

    // ---- Layers 1, 2 (din = 128) ----
    for (int l = 1; l < 3; ++l) {
        const float* const* Q = P + 8 * l;
        agg128<<<N_NODES / 8, 256, 0, stream>>>(x_cur, row_ptr, csr_src, csr_val, Q[0], Q[1], aggr);
        node_kernel<HDIM><<<N_NODES / 8, 128, 0, stream>>>(aggr, Q[2], Q[3], Q[4], Q[5], Q[6], Q[7], x_cur);
    }

    // ---- Pooling ----
    hipMemsetAsync(pool, 0, N_GRAPHS * HDIM * sizeof(float) + N_GRAPHS * sizeof(int), stream);
    pool_partial<<<(N_NODES + NPB - 1) / NPB, 128, 0, stream>>>(x_cur, batch, pool, cnt);
    pool_final<<<N_GRAPHS, HDIM, 0, stream>>>(pool, cnt, out);
}

// Round 4
// 646.823 us; speedup vs baseline: 3.8373x; 1.7153x over previous
//
#include <hip/hip_runtime.h>

#define N_NODES 200000
#define N_EDGES 400000
#define N_GRAPHS 64
#define HDIM 128
#define INDIM 5
#define LN_EPS 1e-5f

typedef __attribute__((ext_vector_type(8))) short short8;
typedef __attribute__((ext_vector_type(4))) float f32x4;

__device__ __forceinline__ void split_bf(float v, short& h, short& l) {
    unsigned u = __builtin_bit_cast(unsigned, v);
    unsigned r = (u + 0x7FFFu + ((u >> 16) & 1u)) >> 16;
    h = (short)r;
    float hf = __builtin_bit_cast(float, r << 16);
    float d = v - hf;
    unsigned u2 = __builtin_bit_cast(unsigned, d);
    unsigned r2 = (u2 + 0x7FFFu + ((u2 >> 16) & 1u)) >> 16;
    l = (short)r2;
}

// ---------------- CSR build ----------------

__global__ void hist_kernel(const int* __restrict__ ei, int* __restrict__ deg) {
    int e = blockIdx.x * blockDim.x + threadIdx.x;
    if (e < N_EDGES) atomicAdd(&deg[ei[N_EDGES + e]], 1);
}

#define SCAN_CHUNK 1024
#define SCAN_BLOCKS ((N_NODES + SCAN_CHUNK - 1) / SCAN_CHUNK)  // 196

__global__ __launch_bounds__(256) void scan_phaseA(const int* __restrict__ deg, int* __restrict__ bsums) {
    __shared__ int red[256];
    int t = threadIdx.x;
    int base = blockIdx.x * SCAN_CHUNK + t * 4;
    int s = 0;
#pragma unroll
    for (int k = 0; k < 4; ++k) {
        int i = base + k;
        s += (i < N_NODES) ? deg[i] : 0;
    }
    red[t] = s;
    __syncthreads();
    for (int off = 128; off; off >>= 1) {
        if (t < off) red[t] += red[t + off];
        __syncthreads();
    }
    if (t == 0) bsums[blockIdx.x] = red[0];
}

__global__ void scan_phaseB(int* __restrict__ bsums, int* __restrict__ row_ptr) {
    if (threadIdx.x == 0) {
        int run = 0;
        for (int i = 0; i < SCAN_BLOCKS; ++i) {
            int v = bsums[i];
            bsums[i] = run;
            run += v;
        }
        row_ptr[N_NODES] = run;
    }
}

__global__ __launch_bounds__(256) void scan_phaseC(const int* __restrict__ deg,
                                                   const int* __restrict__ bsums,
                                                   int* __restrict__ row_ptr) {
    __shared__ int ts[256];
    int t = threadIdx.x;
    int base = blockIdx.x * SCAN_CHUNK + t * 4;
    int v[4];
    int s = 0;
#pragma unroll
    for (int k = 0; k < 4; ++k) {
        int i = base + k;
        v[k] = (i < N_NODES) ? deg[i] : 0;
        s += v[k];
    }
    ts[t] = s;
    __syncthreads();
    for (int off = 1; off < 256; off <<= 1) {
        int add = (t >= off) ? ts[t - off] : 0;
        __syncthreads();
        ts[t] += add;
        __syncthreads();
    }
    int run = bsums[blockIdx.x] + ts[t] - s;
#pragma unroll
    for (int k = 0; k < 4; ++k) {
        int i = base + k;
        if (i < N_NODES) row_ptr[i] = run;
        run += v[k];
    }
}

__global__ void scatter_kernel(const int* __restrict__ ei, const float* __restrict__ ea,
                               const int* __restrict__ row_ptr, int* __restrict__ cursor,
                               int* __restrict__ csr_src, float* __restrict__ csr_val) {
    int e = blockIdx.x * blockDim.x + threadIdx.x;
    if (e >= N_EDGES) return;
    int d = ei[N_EDGES + e];
    int pos = atomicAdd(&cursor[d], 1);
    int slot = row_ptr[d] + pos;
    csr_src[slot] = ei[e];
    csr_val[slot] = ea[e];
}

// ---------------- Aggregation (gather, no atomics) ----------------

__global__ __launch_bounds__(256) void agg5(const float* __restrict__ x,
                                            const int* __restrict__ row_ptr,
                                            const int* __restrict__ csr_src,
                                            const float* __restrict__ csr_val,
                                            const float* __restrict__ ew, const float* __restrict__ eb,
                                            float* __restrict__ aggr) {
    int node = blockIdx.x * blockDim.x + threadIdx.x;
    if (node >= N_NODES) return;
    float w[INDIM], b[INDIM], acc[INDIM];
#pragma unroll
    for (int j = 0; j < INDIM; ++j) {
        w[j] = ew[j];
        b[j] = eb[j];
        acc[j] = x[node * INDIM + j];
    }
    int beg = row_ptr[node], end = row_ptr[node + 1];
    for (int e = beg; e < end; ++e) {
        int s = csr_src[e];
        float a = csr_val[e];
#pragma unroll
        for (int j = 0; j < INDIM; ++j)
            acc[j] += fmaxf(x[s * INDIM + j] + a * w[j] + b[j], 0.f);
    }
#pragma unroll
    for (int j = 0; j < INDIM; ++j) aggr[node * INDIM + j] = acc[j];
}

__global__ __launch_bounds__(256) void agg128(const float* __restrict__ x,
                                              const int* __restrict__ row_ptr,
                                              const int* __restrict__ csr_src,
                                              const float* __restrict__ csr_val,
                                              const float* __restrict__ ew, const float* __restrict__ eb,
                                              float* __restrict__ aggr) {
    int t = threadIdx.x;
    int node = blockIdx.x * 8 + (t >> 5);
    int c = (t & 31) * 4;
    float4 w4 = *(const float4*)&ew[c];
    float4 b4 = *(const float4*)&eb[c];
    float4 acc = *(const float4*)&x[(size_t)node * HDIM + c];
    int beg = row_ptr[node], end = row_ptr[node + 1];
    for (int e = beg; e < end; ++e) {
        int s = csr_src[e];
        float a = csr_val[e];
        float4 xv = *(const float4*)&x[(size_t)s * HDIM + c];
        acc.x += fmaxf(xv.x + a * w4.x + b4.x, 0.f);
        acc.y += fmaxf(xv.y + a * w4.y + b4.y, 0.f);
        acc.z += fmaxf(xv.z + a * w4.z + b4.z, 0.f);
        acc.w += fmaxf(xv.w + a * w4.w + b4.w, 0.f);
    }
    *(float4*)&aggr[(size_t)node * HDIM + c] = acc;
}

// ---------------- Weight packing into MFMA B-fragment order ----------------
__global__ void pack_w(const float* __restrict__ W, short* __restrict__ hi, short* __restrict__ lo,
                       int din, int KP) {
    int idx = blockIdx.x * 256 + threadIdx.x;
    if (idx >= KP * 128) return;
    int j = idx & 7;
    int lane = (idx >> 3) & 63;
    int rest = idx >> 9;
    int KS = KP >> 5;
    int kstep = rest % KS;
    int tile = rest / KS;
    int k = kstep * 32 + ((lane >> 4) * 8) + j;
    int n = tile * 16 + (lane & 15);
    float v = (k < din) ? W[k * 128 + n] : 0.f;
    short h, l;
    split_bf(v, h, l);
    hi[idx] = h;
    lo[idx] = l;
}

// ---------------- Fused MFMA MLP + LayerNorm + ReLU ----------------
#define LDA 132
template <int KP1>
__global__ __launch_bounds__(256) void node_mfma(const float* __restrict__ hin, int din,
                                                 const short* __restrict__ w1h, const short* __restrict__ w1l,
                                                 const float* __restrict__ b1,
                                                 const short* __restrict__ w2h, const short* __restrict__ w2l,
                                                 const float* __restrict__ b2,
                                                 const float* __restrict__ g, const float* __restrict__ bt,
                                                 float* __restrict__ xout) {
    __shared__ float A[64 * LDA];
    __shared__ float psum[4][64], psq[4][64], lmu[64], linv[64];
    int tid = threadIdx.x;
    int node0 = blockIdx.x * 64;

    if (KP1 == 128) {
#pragma unroll
        for (int i = 0; i < 8; ++i) {
            int g4 = tid + 256 * i;
            int flat = g4 * 4;
            int row = flat >> 7, col = flat & 127;
            float4 v = *(const float4*)&hin[(size_t)(node0 + row) * 128 + col];
            *(float4*)&A[row * LDA + col] = v;
        }
    } else {
#pragma unroll
        for (int i = 0; i < 8; ++i) {
            int idx = tid + 256 * i;  // 64 x 32
            int row = idx >> 5, col = idx & 31;
            A[row * LDA + col] = (col < din) ? hin[(node0 + row) * din + col] : 0.f;
        }
    }
    __syncthreads();

    int wv = tid >> 6, lane = tid & 63;
    int mrow = lane & 15, q = lane >> 4;
    int arow = wv * 16 + mrow;

    float b1v[8], b2v[8];
#pragma unroll
    for (int t = 0; t < 8; ++t) {
        b1v[t] = b1[t * 16 + mrow];
        b2v[t] = b2[t * 16 + mrow];
    }

    // ---- GEMM1 ----
    f32x4 acc[8];
#pragma unroll
    for (int t = 0; t < 8; ++t) acc[t] = (f32x4){0.f, 0.f, 0.f, 0.f};
    constexpr int KS1 = KP1 / 32;
#pragma unroll
    for (int ks = 0; ks < KS1; ++ks) {
        float4 v0 = *(float4*)&A[arow * LDA + ks * 32 + q * 8];
        float4 v1 = *(float4*)&A[arow * LDA + ks * 32 + q * 8 + 4];
        float av[8] = {v0.x, v0.y, v0.z, v0.w, v1.x, v1.y, v1.z, v1.w};
        short8 ah, al;
#pragma unroll
        for (int j = 0; j < 8; ++j) {
            short h, l;
            split_bf(av[j], h, l);
            ah[j] = h;
            al[j] = l;
        }
#pragma unroll
        for (int t = 0; t < 8; ++t) {
            short8 bh = *(const short8*)&w1h[(((size_t)t * KS1 + ks) * 64 + lane) * 8];
            short8 bl = *(const short8*)&w1l[(((size_t)t * KS1 + ks) * 64 + lane) * 8];
            acc[t] = __builtin_amdgcn_mfma_f32_16x16x32_bf16(ah, bh, acc[t], 0, 0, 0);
            acc[t] = __builtin_amdgcn_mfma_f32_16x16x32_bf16(ah, bl, acc[t], 0, 0, 0);
            acc[t] = __builtin_amdgcn_mfma_f32_16x16x32_bf16(al, bh, acc[t], 0, 0, 0);
        }
    }
#pragma unroll
    for (int t = 0; t < 8; ++t)
#pragma unroll
        for (int r = 0; r < 4; ++r) {
            int row = wv * 16 + q * 4 + r;
            int col = t * 16 + mrow;
            A[row * LDA + col] = fmaxf(acc[t][r] + b1v[t], 0.f);
        }

    // ---- GEMM2 (K=128) ----
#pragma unroll
    for (int t = 0; t < 8; ++t) acc[t] = (f32x4){0.f, 0.f, 0.f, 0.f};
#pragma unroll
    for (int ks = 0; ks < 4; ++ks) {
        float4 v0 = *(float4*)&A[arow * LDA + ks * 32 + q * 8];
        float4 v1 = *(float4*)&A[arow * LDA + ks * 32 + q * 8 + 4];
        float av[8] = {v0.x, v0.y, v0.z, v0.w, v1.x, v1.y, v1.z, v1.w};
        short8 ah, al;
#pragma unroll
        for (int j = 0; j < 8; ++j) {
            short h, l;
            split_bf(av[j], h, l);
            ah[j] = h;
            al[j] = l;
        }
#pragma unroll
        for (int t = 0; t < 8; ++t) {
            short8 bh = *(const short8*)&w2h[(((size_t)t * 4 + ks) * 64 + lane) * 8];
            short8 bl = *(const short8*)&w2l[(((size_t)t * 4 + ks) * 64 + lane) * 8];
            acc[t] = __builtin_amdgcn_mfma_f32_16x16x32_bf16(ah, bh, acc[t], 0, 0, 0);
            acc[t] = __builtin_amdgcn_mfma_f32_16x16x32_bf16(ah, bl, acc[t], 0, 0, 0);
            acc[t] = __builtin_amdgcn_mfma_f32_16x16x32_bf16(al, bh, acc[t], 0, 0, 0);
        }
    }
#pragma unroll
    for (int t = 0; t < 8; ++t)
#pragma unroll
        for (int r = 0; r < 4; ++r) {
            int row = wv * 16 + q * 4 + r;
            int col = t * 16 + mrow;
            A[row * LDA + col] = acc[t][r] + b2v[t];
        }
    __syncthreads();

    // ---- LayerNorm ----
    {
        int row = tid & 63, seg = tid >> 6;
        float s = 0.f, sq = 0.f;
#pragma unroll
        for (int i = 0; i < 8; ++i) {
            float4 v = *(float4*)&A[row * LDA + seg * 32 + i * 4];
            s += v.x + v.y + v.z + v.w;
            sq += v.x * v.x + v.y * v.y + v.z * v.z + v.w * v.w;
        }
        psum[seg][row] = s;
        psq[seg][row] = sq;
    }
    __syncthreads();
    if (tid < 64) {
        float s = psum[0][tid] + psum[1][tid] + psum[2][tid] + psum[3][tid];
        float sq = psq[0][tid] + psq[1][tid] + psq[2][tid] + psq[3][tid];
        float mu = s * (1.f / HDIM);
        float var = sq * (1.f / HDIM) - mu * mu;
        lmu[tid] = mu;
        linv[tid] = rsqrtf(var + LN_EPS);
    }
    __syncthreads();

    int colbase = (tid * 4) & 127;
    float4 gv = *(const float4*)&g[colbase];
    float4 btv = *(const float4*)&bt[colbase];
#pragma unroll
    for (int i = 0; i < 8; ++i) {
        int row = (tid >> 5) + 8 * i;
        float4 v = *(float4*)&A[row * LDA + colbase];
        float mu = lmu[row], inv = linv[row];
        float4 o;
        o.x = fmaxf((v.x - mu) * inv * gv.x + btv.x, 0.f);
        o.y = fmaxf((v.y - mu) * inv * gv.y + btv.y, 0.f);
        o.z = fmaxf((v.z - mu) * inv * gv.z + btv.z, 0.f);
        o.w = fmaxf((v.w - mu) * inv * gv.w + btv.w, 0.f);
        *(float4*)&xout[(size_t)(node0 + row) * 128 + colbase] = o;
    }
}

// ---------------- Pooling ----------------
#define NPB 256
__global__ __launch_bounds__(128) void pool_partial(const float* __restrict__ x,
                                                    const int* __restrict__ batch,
                                                    float* __restrict__ pool, int* __restrict__ cnt) {
    int j = threadIdx.x;
    int start = blockIdx.x * NPB;
    if (start >= N_NODES) return;
    int end = min(start + NPB, N_NODES);
    int cur = batch[start];
    float acc = 0.f;
    int localcnt = 0;
    for (int i = start; i < end; ++i) {
        int gi = batch[i];
        if (gi != cur) {
            unsafeAtomicAdd(&pool[cur * HDIM + j], acc);
            if (j == 0) atomicAdd(&cnt[cur], localcnt);
            acc = 0.f; localcnt = 0; cur = gi;
        }
        acc += x[i * HDIM + j];
        ++localcnt;
    }
    unsafeAtomicAdd(&pool[cur * HDIM + j], acc);
    if (j == 0) atomicAdd(&cnt[cur], localcnt);
}

__global__ void pool_final(const float* __restrict__ pool, const int* __restrict__ cnt,
                           float* __restrict__ out) {
    int g = blockIdx.x, j = threadIdx.x;
    float add = pool[g * HDIM + j];
    float c = (float)max(cnt[g], 1);
    out[g * (2 * HDIM) + j] = add / c;
    out[g * (2 * HDIM) + HDIM + j] = add;
}

extern "C" void kernel_launch(void* const* d_in, const int* in_sizes, int n_in,
                              void* d_out, int out_size, void* d_ws, size_t ws_size,
                              hipStream_t stream) {
    const float* x_in = (const float*)d_in[0];
    const int* ei = (const int*)d_in[1];
    const float* ea = (const float*)d_in[2];
    const int* batch = (const int*)d_in[3];
    const float* P[24];
    for (int i = 0; i < 24; ++i) P[i] = (const float*)d_in[4 + i];

    float* x_cur = (float*)d_ws;
    float* aggr = x_cur + (size_t)N_NODES * HDIM;
    float* pool = aggr + (size_t)N_NODES * HDIM;
    int* cnt = (int*)(pool + N_GRAPHS * HDIM);
    int* deg = cnt + N_GRAPHS;
    int* row_ptr = deg + N_NODES;
    int* bsums = row_ptr + N_NODES + 1;
    int* csr_src = bsums + 256;
    float* csr_val = (float*)(csr_src + N_EDGES);
    short* wp = (short*)(((uintptr_t)(csr_val + N_EDGES) + 15) & ~(uintptr_t)15);
    float* out = (float*)d_out;

    short *w1h[3], *w1l[3], *w2h[3], *w2l[3];
    for (int l = 0; l < 3; ++l) {
        w1h[l] = wp + (size_t)l * 65536;
        w1l[l] = w1h[l] + 16384;
        w2h[l] = w1l[l] + 16384;
        w2l[l] = w2h[l] + 16384;
    }

    hipMemsetAsync(deg, 0, N_NODES * sizeof(int), stream);
    hist_kernel<<<(N_EDGES + 255) / 256, 256, 0, stream>>>(ei, deg);
    scan_phaseA<<<SCAN_BLOCKS, 256, 0, stream>>>(deg, bsums);
    scan_phaseB<<<1, 64, 0, stream>>>(bsums, row_ptr);
    scan_phaseC<<<SCAN_BLOCKS, 256, 0, stream>>>(deg, bsums, row_ptr);
    hipMemsetAsync(deg, 0, N_NODES * sizeof(int), stream);
    scatter_kernel<<<(N_EDGES + 255) / 256, 256, 0, stream>>>(ei, ea, row_ptr, deg, csr_src, csr_val);

    pack_w<<<16, 256, 0, stream>>>(P[2], w1h[0], w1l[0], INDIM, 32);
    pack_w<<<64, 256, 0, stream>>>(P[4], w2h[0], w2l[0], 128, 128);
    for (int l = 1; l < 3; ++l) {
        pack_w<<<64, 256, 0, stream>>>(P[8 * l + 2], w1h[l], w1l[l], 128, 128);
        pack_w<<<64, 256, 0, stream>>>(P[8 * l + 4], w2h[l], w2l[l], 128, 128);
    }

    agg5<<<(N_NODES + 255) / 256, 256, 0, stream>>>(x_in, row_ptr, csr_src, csr_val, P[0], P[1], aggr);
    node_mfma<32><<<N_NODES / 64, 256, 0, stream>>>(aggr, INDIM, w1h[0], w1l[0], P[3],
                                                    w2h[0], w2l[0], P[5], P[6], P[7], x_cur);

    for (int l = 1; l < 3; ++l) {
        const float* const* Q = P + 8 * l;
        agg128<<<N_NODES / 8, 256, 0, stream>>>(x_cur, row_ptr, csr_src, csr_val, Q[0], Q[1], aggr);
        node_mfma<128><<<N_NODES / 64, 256, 0, stream>>>(aggr, HDIM, w1h[l], w1l[l], Q[3],
                                                         w2h[l], w2l[l], Q[5], Q[6], Q[7], x_cur);
    }

    hipMemsetAsync(pool, 0, N_GRAPHS * HDIM * sizeof(float) + N_GRAPHS * sizeof(int), stream);
    pool_partial<<<(N_NODES + NPB - 1) / NPB, 128, 0, stream>>>(x_cur, batch, pool, cnt);
    pool_final<<<N_GRAPHS, HDIM, 0, stream>>>(pool, cnt, out);
}

// Round 5
// 516.326 us; speedup vs baseline: 4.8072x; 1.2527x over previous
//
#include <hip/hip_runtime.h>

#define N_NODES 200000
#define N_EDGES 400000
#define N_GRAPHS 64
#define HDIM 128
#define INDIM 5
#define LN_EPS 1e-5f

typedef __attribute__((ext_vector_type(8))) short short8;
typedef __attribute__((ext_vector_type(4))) float f32x4;

__device__ __forceinline__ void split_bf(float v, short& h, short& l) {
    unsigned u = __builtin_bit_cast(unsigned, v);
    unsigned r = (u + 0x7FFFu + ((u >> 16) & 1u)) >> 16;
    h = (short)r;
    float hf = __builtin_bit_cast(float, r << 16);
    float d = v - hf;
    unsigned u2 = __builtin_bit_cast(unsigned, d);
    unsigned r2 = (u2 + 0x7FFFu + ((u2 >> 16) & 1u)) >> 16;
    l = (short)r2;
}

__device__ __forceinline__ short to_bf(float v) {
    unsigned u = __builtin_bit_cast(unsigned, v);
    return (short)((u + 0x7FFFu + ((u >> 16) & 1u)) >> 16);
}

// ---------------- CSR build ----------------

__global__ void hist_kernel(const int* __restrict__ ei, int* __restrict__ deg) {
    int e = blockIdx.x * blockDim.x + threadIdx.x;
    if (e < N_EDGES) atomicAdd(&deg[ei[N_EDGES + e]], 1);
}

#define SCAN_CHUNK 1024
#define SCAN_BLOCKS ((N_NODES + SCAN_CHUNK - 1) / SCAN_CHUNK)  // 196

__global__ __launch_bounds__(256) void scan_phaseA(const int* __restrict__ deg, int* __restrict__ bsums) {
    __shared__ int red[256];
    int t = threadIdx.x;
    int base = blockIdx.x * SCAN_CHUNK + t * 4;
    int s = 0;
#pragma unroll
    for (int k = 0; k < 4; ++k) {
        int i = base + k;
        s += (i < N_NODES) ? deg[i] : 0;
    }
    red[t] = s;
    __syncthreads();
    for (int off = 128; off; off >>= 1) {
        if (t < off) red[t] += red[t + off];
        __syncthreads();
    }
    if (t == 0) bsums[blockIdx.x] = red[0];
}

__global__ void scan_phaseB(int* __restrict__ bsums, int* __restrict__ row_ptr) {
    if (threadIdx.x == 0) {
        int run = 0;
        for (int i = 0; i < SCAN_BLOCKS; ++i) {
            int v = bsums[i];
            bsums[i] = run;
            run += v;
        }
        row_ptr[N_NODES] = run;
    }
}

__global__ __launch_bounds__(256) void scan_phaseC(const int* __restrict__ deg,
                                                   const int* __restrict__ bsums,
                                                   int* __restrict__ row_ptr) {
    __shared__ int ts[256];
    int t = threadIdx.x;
    int base = blockIdx.x * SCAN_CHUNK + t * 4;
    int v[4];
    int s = 0;
#pragma unroll
    for (int k = 0; k < 4; ++k) {
        int i = base + k;
        v[k] = (i < N_NODES) ? deg[i] : 0;
        s += v[k];
    }
    ts[t] = s;
    __syncthreads();
    for (int off = 1; off < 256; off <<= 1) {
        int add = (t >= off) ? ts[t - off] : 0;
        __syncthreads();
        ts[t] += add;
        __syncthreads();
    }
    int run = bsums[blockIdx.x] + ts[t] - s;
#pragma unroll
    for (int k = 0; k < 4; ++k) {
        int i = base + k;
        if (i < N_NODES) row_ptr[i] = run;
        run += v[k];
    }
}

__global__ void scatter_kernel(const int* __restrict__ ei, const float* __restrict__ ea,
                               const int* __restrict__ row_ptr, int* __restrict__ cursor,
                               int* __restrict__ csr_src, float* __restrict__ csr_val) {
    int e = blockIdx.x * blockDim.x + threadIdx.x;
    if (e >= N_EDGES) return;
    int d = ei[N_EDGES + e];
    int pos = atomicAdd(&cursor[d], 1);
    int slot = row_ptr[d] + pos;
    csr_src[slot] = ei[e];
    csr_val[slot] = ea[e];
}

// ---------------- Weight packing into MFMA B-fragment order (hi only) ----------------
__global__ void pack_w(const float* __restrict__ W, short* __restrict__ hi, int din, int KP) {
    int idx = blockIdx.x * 256 + threadIdx.x;
    if (idx >= KP * 128) return;
    int j = idx & 7;
    int lane = (idx >> 3) & 63;
    int rest = idx >> 9;
    int KS = KP >> 5;
    int kstep = rest % KS;
    int tile = rest / KS;
    int k = kstep * 32 + ((lane >> 4) * 8) + j;
    int n = tile * 16 + (lane & 15);
    float v = (k < din) ? W[k * 128 + n] : 0.f;
    hi[idx] = to_bf(v);
}

// ---------------- Fused layer: gather-aggregate + MFMA MLP + LayerNorm + ReLU (+pool) ----------------
#define LDA 132
template <int KP1, bool POOL>
__global__ __launch_bounds__(256) void layer_fused(
    const float* __restrict__ xin, const int* __restrict__ row_ptr,
    const int* __restrict__ csr_src, const float* __restrict__ csr_val,
    const float* __restrict__ ew, const float* __restrict__ eb,
    const short* __restrict__ w1h, const float* __restrict__ b1,
    const short* __restrict__ w2h, const float* __restrict__ b2,
    const float* __restrict__ g, const float* __restrict__ bt,
    float* __restrict__ xout,
    const int* __restrict__ batch, float* __restrict__ pool, int* __restrict__ cnt) {
    __shared__ float A[64 * LDA];
    __shared__ float psum[4][64], psq[4][64], lmu[64], linv[64];
    __shared__ int bidx[64];
    int tid = threadIdx.x;
    int node0 = blockIdx.x * 64;

    // ---- gather phase: h = x + sum_edges relu(x[src] + a*ew + eb) -> LDS A ----
    if (KP1 == 128) {
        int gid = tid >> 5, c = (tid & 31) * 4;
        float4 w4 = *(const float4*)&ew[c];
        float4 b4 = *(const float4*)&eb[c];
#pragma unroll
        for (int rep = 0; rep < 8; ++rep) {
            int row = rep * 8 + gid;
            int node = node0 + row;
            float4 acc = *(const float4*)&xin[(size_t)node * 128 + c];
            int beg = row_ptr[node], end = row_ptr[node + 1];
            for (int e = beg; e < end; ++e) {
                int s = csr_src[e];
                float a = csr_val[e];
                float4 xv = *(const float4*)&xin[(size_t)s * 128 + c];
                acc.x += fmaxf(xv.x + a * w4.x + b4.x, 0.f);
                acc.y += fmaxf(xv.y + a * w4.y + b4.y, 0.f);
                acc.z += fmaxf(xv.z + a * w4.z + b4.z, 0.f);
                acc.w += fmaxf(xv.w + a * w4.w + b4.w, 0.f);
            }
            *(float4*)&A[row * LDA + c] = acc;
        }
    } else {
        // din = 5, KP1 = 32
        if (tid < 64) {
            int node = node0 + tid;
            float w[INDIM], bb[INDIM], acc[INDIM];
#pragma unroll
            for (int j = 0; j < INDIM; ++j) {
                w[j] = ew[j];
                bb[j] = eb[j];
                acc[j] = xin[node * INDIM + j];
            }
            int beg = row_ptr[node], end = row_ptr[node + 1];
            for (int e = beg; e < end; ++e) {
                int s = csr_src[e];
                float a = csr_val[e];
#pragma unroll
                for (int j = 0; j < INDIM; ++j)
                    acc[j] += fmaxf(xin[s * INDIM + j] + a * w[j] + bb[j], 0.f);
            }
#pragma unroll
            for (int j = 0; j < INDIM; ++j) A[tid * LDA + j] = acc[j];
#pragma unroll
            for (int j = INDIM; j < 32; ++j) A[tid * LDA + j] = 0.f;
        }
    }
    if (POOL && tid < 64) bidx[tid] = batch[node0 + tid];
    __syncthreads();

    int wv = tid >> 6, lane = tid & 63;
    int mrow = lane & 15, q = lane >> 4;
    int arow = wv * 16 + mrow;

    float b1v[8], b2v[8];
#pragma unroll
    for (int t = 0; t < 8; ++t) {
        b1v[t] = b1[t * 16 + mrow];
        b2v[t] = b2[t * 16 + mrow];
    }

    // ---- GEMM1 (exact-A hi/lo x bf16-B: 2 MFMAs) ----
    f32x4 acc[8];
#pragma unroll
    for (int t = 0; t < 8; ++t) acc[t] = (f32x4){0.f, 0.f, 0.f, 0.f};
    constexpr int KS1 = KP1 / 32;
#pragma unroll
    for (int ks = 0; ks < KS1; ++ks) {
        float4 v0 = *(float4*)&A[arow * LDA + ks * 32 + q * 8];
        float4 v1 = *(float4*)&A[arow * LDA + ks * 32 + q * 8 + 4];
        float av[8] = {v0.x, v0.y, v0.z, v0.w, v1.x, v1.y, v1.z, v1.w};
        short8 ah, al;
#pragma unroll
        for (int j = 0; j < 8; ++j) {
            short h, l;
            split_bf(av[j], h, l);
            ah[j] = h;
            al[j] = l;
        }
#pragma unroll
        for (int t = 0; t < 8; ++t) {
            short8 bh = *(const short8*)&w1h[(((size_t)t * KS1 + ks) * 64 + lane) * 8];
            acc[t] = __builtin_amdgcn_mfma_f32_16x16x32_bf16(ah, bh, acc[t], 0, 0, 0);
            acc[t] = __builtin_amdgcn_mfma_f32_16x16x32_bf16(al, bh, acc[t], 0, 0, 0);
        }
    }
#pragma unroll
    for (int t = 0; t < 8; ++t)
#pragma unroll
        for (int r = 0; r < 4; ++r) {
            int row = wv * 16 + q * 4 + r;
            int col = t * 16 + mrow;
            A[row * LDA + col] = fmaxf(acc[t][r] + b1v[t], 0.f);
        }

    // ---- GEMM2 (K = 128) ----
#pragma unroll
    for (int t = 0; t < 8; ++t) acc[t] = (f32x4){0.f, 0.f, 0.f, 0.f};
#pragma unroll
    for (int ks = 0; ks < 4; ++ks) {
        float4 v0 = *(float4*)&A[arow * LDA + ks * 32 + q * 8];
        float4 v1 = *(float4*)&A[arow * LDA + ks * 32 + q * 8 + 4];
        float av[8] = {v0.x, v0.y, v0.z, v0.w, v1.x, v1.y, v1.z, v1.w};
        short8 ah, al;
#pragma unroll
        for (int j = 0; j < 8; ++j) {
            short h, l;
            split_bf(av[j], h, l);
            ah[j] = h;
            al[j] = l;
        }
#pragma unroll
        for (int t = 0; t < 8; ++t) {
            short8 bh = *(const short8*)&w2h[(((size_t)t * 4 + ks) * 64 + lane) * 8];
            acc[t] = __builtin_amdgcn_mfma_f32_16x16x32_bf16(ah, bh, acc[t], 0, 0, 0);
            acc[t] = __builtin_amdgcn_mfma_f32_16x16x32_bf16(al, bh, acc[t], 0, 0, 0);
        }
    }
#pragma unroll
    for (int t = 0; t < 8; ++t)
#pragma unroll
        for (int r = 0; r < 4; ++r) {
            int row = wv * 16 + q * 4 + r;
            int col = t * 16 + mrow;
            A[row * LDA + col] = acc[t][r] + b2v[t];
        }
    __syncthreads();

    // ---- LayerNorm stats ----
    {
        int row = tid & 63, seg = tid >> 6;
        float s = 0.f, sq = 0.f;
#pragma unroll
        for (int i = 0; i < 8; ++i) {
            float4 v = *(float4*)&A[row * LDA + seg * 32 + i * 4];
            s += v.x + v.y + v.z + v.w;
            sq += v.x * v.x + v.y * v.y + v.z * v.z + v.w * v.w;
        }
        psum[seg][row] = s;
        psq[seg][row] = sq;
    }
    __syncthreads();
    if (tid < 64) {
        float s = psum[0][tid] + psum[1][tid] + psum[2][tid] + psum[3][tid];
        float sq = psq[0][tid] + psq[1][tid] + psq[2][tid] + psq[3][tid];
        float mu = s * (1.f / HDIM);
        float var = sq * (1.f / HDIM) - mu * mu;
        lmu[tid] = mu;
        linv[tid] = rsqrtf(var + LN_EPS);
    }
    __syncthreads();

    // ---- scale/shift + ReLU ----
    int colbase = (tid * 4) & 127;
    float4 gv = *(const float4*)&g[colbase];
    float4 btv = *(const float4*)&bt[colbase];
#pragma unroll
    for (int i = 0; i < 8; ++i) {
        int row = (tid >> 5) + 8 * i;
        float4 v = *(float4*)&A[row * LDA + colbase];
        float mu = lmu[row], inv = linv[row];
        float4 o;
        o.x = fmaxf((v.x - mu) * inv * gv.x + btv.x, 0.f);
        o.y = fmaxf((v.y - mu) * inv * gv.y + btv.y, 0.f);
        o.z = fmaxf((v.z - mu) * inv * gv.z + btv.z, 0.f);
        o.w = fmaxf((v.w - mu) * inv * gv.w + btv.w, 0.f);
        if (POOL) {
            *(float4*)&A[row * LDA + colbase] = o;
        } else {
            *(float4*)&xout[(size_t)(node0 + row) * 128 + colbase] = o;
        }
    }

    // ---- fused pooling (layer 2): segmented sum over sorted batch ----
    if (POOL) {
        __syncthreads();
        if (tid < 128) {
            int col = tid;
            float acc2 = 0.f;
            int cur = bidx[0];
            for (int r = 0; r < 64; ++r) {
                int gi = bidx[r];
                if (gi != cur) {
                    unsafeAtomicAdd(&pool[cur * HDIM + col], acc2);
                    acc2 = 0.f;
                    cur = gi;
                }
                acc2 += A[r * LDA + col];
            }
            unsafeAtomicAdd(&pool[cur * HDIM + col], acc2);
        } else if (tid == 255) {
            int cur = bidx[0], c = 0;
            for (int r = 0; r < 64; ++r) {
                if (bidx[r] != cur) {
                    atomicAdd(&cnt[cur], c);
                    c = 0;
                    cur = bidx[r];
                }
                ++c;
            }
            atomicAdd(&cnt[cur], c);
        }
    }
}

__global__ void pool_final(const float* __restrict__ pool, const int* __restrict__ cnt,
                           float* __restrict__ out) {
    int g = blockIdx.x, j = threadIdx.x;
    float add = pool[g * HDIM + j];
    float c = (float)max(cnt[g], 1);
    out[g * (2 * HDIM) + j] = add / c;
    out[g * (2 * HDIM) + HDIM + j] = add;
}

extern "C" void kernel_launch(void* const* d_in, const int* in_sizes, int n_in,
                              void* d_out, int out_size, void* d_ws, size_t ws_size,
                              hipStream_t stream) {
    const float* x_in = (const float*)d_in[0];
    const int* ei = (const int*)d_in[1];
    const float* ea = (const float*)d_in[2];
    const int* batch = (const int*)d_in[3];
    const float* P[24];
    for (int i = 0; i < 24; ++i) P[i] = (const float*)d_in[4 + i];
    // per layer l (base 8l): 0=ew 1=eb 2=w1 3=b1 4=w2 5=b2 6=g 7=bt

    float* x_a = (float*)d_ws;                            // N*128
    float* x_b = x_a + (size_t)N_NODES * HDIM;            // N*128
    float* pool = x_b + (size_t)N_NODES * HDIM;           // G*128 } zeroed
    int* cnt = (int*)(pool + N_GRAPHS * HDIM);            // G     } together
    int* deg = cnt + N_GRAPHS;                            // N     } (one
    int* cursor = deg + N_NODES;                          // N     } memset)
    int* row_ptr = cursor + N_NODES;                      // N+1
    int* bsums = row_ptr + N_NODES + 1;                   // pad 256
    int* csr_src = bsums + 256;                           // E
    float* csr_val = (float*)(csr_src + N_EDGES);         // E
    short* wp = (short*)(((uintptr_t)(csr_val + N_EDGES) + 15) & ~(uintptr_t)15);
    float* out = (float*)d_out;

    // packed weights (hi only): per layer w1h (16384 cap), w2h (16384)
    short *w1h[3], *w2h[3];
    for (int l = 0; l < 3; ++l) {
        w1h[l] = wp + (size_t)l * 32768;
        w2h[l] = w1h[l] + 16384;
    }

    // ---- single memset: pool + cnt + deg + cursor ----
    hipMemsetAsync(pool, 0,
                   (N_GRAPHS * HDIM + N_GRAPHS + 2 * N_NODES) * sizeof(int), stream);

    // ---- CSR build ----
    hist_kernel<<<(N_EDGES + 255) / 256, 256, 0, stream>>>(ei, deg);
    scan_phaseA<<<SCAN_BLOCKS, 256, 0, stream>>>(deg, bsums);
    scan_phaseB<<<1, 64, 0, stream>>>(bsums, row_ptr);
    scan_phaseC<<<SCAN_BLOCKS, 256, 0, stream>>>(deg, bsums, row_ptr);
    scatter_kernel<<<(N_EDGES + 255) / 256, 256, 0, stream>>>(ei, ea, row_ptr, cursor, csr_src, csr_val);

    // ---- pack weights (bf16 hi) ----
    pack_w<<<16, 256, 0, stream>>>(P[2], w1h[0], INDIM, 32);
    pack_w<<<64, 256, 0, stream>>>(P[4], w2h[0], 128, 128);
    for (int l = 1; l < 3; ++l) {
        pack_w<<<64, 256, 0, stream>>>(P[8 * l + 2], w1h[l], 128, 128);
        pack_w<<<64, 256, 0, stream>>>(P[8 * l + 4], w2h[l], 128, 128);
    }

    // ---- fused layers ----
    layer_fused<32, false><<<N_NODES / 64, 256, 0, stream>>>(
        x_in, row_ptr, csr_src, csr_val, P[0], P[1],
        w1h[0], P[3], w2h[0], P[5], P[6], P[7], x_a, nullptr, nullptr, nullptr);
    layer_fused<128, false><<<N_NODES / 64, 256, 0, stream>>>(
        x_a, row_ptr, csr_src, csr_val, P[8], P[9],
        w1h[1], P[11], w2h[1], P[13], P[14], P[15], x_b, nullptr, nullptr, nullptr);
    layer_fused<128, true><<<N_NODES / 64, 256, 0, stream>>>(
        x_b, row_ptr, csr_src, csr_val, P[16], P[17],
        w1h[2], P[19], w2h[2], P[21], P[22], P[23], nullptr, batch, pool, cnt);

    pool_final<<<N_GRAPHS, HDIM, 0, stream>>>(pool, cnt, out);
}